// Round 7
// baseline (762.819 us; speedup 1.0000x reference)
//
#include <hip/hip_runtime.h>
#include <hip/hip_bf16.h>
#include <math.h>

#define D_ 256
#define HEADS_ 8
#define DH_ 32
#define LVLS_ 4
#define PTS_ 4
#define DFF_ 1024
#define LQ_ 900
#define B_ 16
#define S_ 13294
#define MQ (LQ_*B_)      // 14400
#define MV (S_*B_)       // 212704

typedef __attribute__((ext_vector_type(4))) float f32x4;
typedef __attribute__((ext_vector_type(8))) short bf16x8;

static __device__ inline ushort f2bf(float f) {
  __hip_bfloat16 h = __float2bfloat16(f);   // RNE
  union { __hip_bfloat16 h; ushort u; } c; c.h = h;
  return c.u;
}
static __device__ inline float bf2f(ushort u) {
  union { float f; uint u; } c; c.u = (uint)u << 16; return c.f;
}

// ---------------- bf16-MFMA GEMM, LDS-free: Y = act((A [+ X2]) @ W^T + bias) ----------------
// A,X2: [M,K] f32 row-major. W: [N,K] f32 row-major. Y: [M,N] f32 or bf16 (outbf).
// N % 128 == 0, K % 64 == 0. M tail: row-clamped loads, masked writes.
// No LDS, no barriers: fragments are loaded straight from global (wave reads
// 16 rows x 128 B contiguous per fragment -> fully coalesced), converted
// f32->bf16 in-reg. W is L2-resident; A streams once (L3 absorbs re-reads).
// All offsets fit 32-bit (max M*K = 54.4M floats).
__global__ __launch_bounds__(256) void gemm_bf16_kernel(
    const float* __restrict__ A, const float* __restrict__ X2,
    const float* __restrict__ Wm, const float* __restrict__ bias,
    float* __restrict__ Y, int M, int N, int K, int relu, int outbf)
{
  const int tid  = threadIdx.x;
  const int lane = tid & 63;
  const int wid  = tid >> 6;
  const int wr = wid >> 1, wc = wid & 1;     // wave quadrant in 2x2
  const int fr = lane & 15;                  // fragment row within 16
  const int fk = (lane >> 4) << 3;           // k-slice 0,8,16,24
  const int m0 = blockIdx.y * 128, n0 = blockIdx.x * 128;

  f32x4 acc[4][4];
  const f32x4 zero = {0.f, 0.f, 0.f, 0.f};
#pragma unroll
  for (int i = 0; i < 4; ++i)
#pragma unroll
    for (int j = 0; j < 4; ++j) acc[i][j] = zero;

  uint aoff[4];
#pragma unroll
  for (int i = 0; i < 4; ++i) {
    int ar = m0 + wr * 64 + i * 16 + fr;
    if (ar > M - 1) ar = M - 1;              // clamp; write masked in epilogue
    aoff[i] = (uint)ar * (uint)K + fk;
  }
  const uint woff = (uint)(n0 + wc * 64 + fr) * (uint)K + fk;
  const uint wstride = (uint)(16 * K);

#pragma unroll 2
  for (int k0 = 0; k0 < K; k0 += 32) {
    bf16x8 af[4], bfr[4];
#pragma unroll
    for (int i = 0; i < 4; ++i) {
      const float* p = A + aoff[i] + k0;
      float4 lo = *(const float4*)p;
      float4 hi = *(const float4*)(p + 4);
      if (X2) {
        const float* x = X2 + aoff[i] + k0;
        const float4 xl = *(const float4*)x;
        const float4 xh = *(const float4*)(x + 4);
        lo.x += xl.x; lo.y += xl.y; lo.z += xl.z; lo.w += xl.w;
        hi.x += xh.x; hi.y += xh.y; hi.z += xh.z; hi.w += xh.w;
      }
      ushort t[8] __attribute__((aligned(16)));
      t[0]=f2bf(lo.x); t[1]=f2bf(lo.y); t[2]=f2bf(lo.z); t[3]=f2bf(lo.w);
      t[4]=f2bf(hi.x); t[5]=f2bf(hi.y); t[6]=f2bf(hi.z); t[7]=f2bf(hi.w);
      af[i] = *(const bf16x8*)t;
    }
#pragma unroll
    for (int j = 0; j < 4; ++j) {
      const float* p = Wm + woff + j * wstride + k0;
      const float4 lo = *(const float4*)p;
      const float4 hi = *(const float4*)(p + 4);
      ushort t[8] __attribute__((aligned(16)));
      t[0]=f2bf(lo.x); t[1]=f2bf(lo.y); t[2]=f2bf(lo.z); t[3]=f2bf(lo.w);
      t[4]=f2bf(hi.x); t[5]=f2bf(hi.y); t[6]=f2bf(hi.z); t[7]=f2bf(hi.w);
      bfr[j] = *(const bf16x8*)t;
    }
#pragma unroll
    for (int i = 0; i < 4; ++i)
#pragma unroll
      for (int j = 0; j < 4; ++j)
        acc[i][j] = __builtin_amdgcn_mfma_f32_16x16x32_bf16(af[i], bfr[j], acc[i][j], 0, 0, 0);
  }

  // epilogue: C/D layout col = lane&15, row = (lane>>4)*4 + reg
  const int gcolbase = n0 + wc * 64 + fr;
  float bias4[4];
#pragma unroll
  for (int j = 0; j < 4; ++j) bias4[j] = bias[gcolbase + j * 16];
#pragma unroll
  for (int i = 0; i < 4; ++i) {
    const int rb = m0 + wr * 64 + i * 16 + (lane >> 4) * 4;
#pragma unroll
    for (int r = 0; r < 4; ++r) {
      const int grow = rb + r;
      if (grow < M) {
#pragma unroll
        for (int j = 0; j < 4; ++j) {
          float v = acc[i][j][r] + bias4[j];
          if (relu) v = fmaxf(v, 0.f);
          if (outbf) ((ushort*)Y)[(size_t)grow * N + gcolbase + j * 16] = f2bf(v);
          else       Y[(size_t)grow * N + gcolbase + j * 16] = v;
        }
      }
    }
  }
}

// ---------------- generic f32 GEMM: Y = act((X1 [+ X2]) @ W^T + bias) ----------------
__global__ __launch_bounds__(256) void gemm_bias_kernel(
    const float* __restrict__ X1, const float* __restrict__ X2,
    const float* __restrict__ W, const float* __restrict__ bias,
    float* __restrict__ Y, int M, int N, int K, int relu)
{
  __shared__ float As[16][64];
  __shared__ float Ws[16][64];
  const int tid = threadIdx.x;
  const int tx = tid & 15, ty = tid >> 4;
  const int m0 = blockIdx.y * 64, n0 = blockIdx.x * 64;
  float acc[4][4] = {};
  for (int k0 = 0; k0 < K; k0 += 16) {
    const int i   = tid * 4;
    const int row = i >> 4;
    const int col = i & 15;
    const int gr  = m0 + row;
    float4 v = make_float4(0.f, 0.f, 0.f, 0.f);
    if (gr < M) {
      v = *(const float4*)(X1 + (size_t)gr * K + k0 + col);
      if (X2) {
        float4 u = *(const float4*)(X2 + (size_t)gr * K + k0 + col);
        v.x += u.x; v.y += u.y; v.z += u.z; v.w += u.w;
      }
    }
    As[col+0][row] = v.x; As[col+1][row] = v.y; As[col+2][row] = v.z; As[col+3][row] = v.w;
    const float4 wv = *(const float4*)(W + (size_t)(n0 + row) * K + k0 + col);
    Ws[col+0][row] = wv.x; Ws[col+1][row] = wv.y; Ws[col+2][row] = wv.z; Ws[col+3][row] = wv.w;
    __syncthreads();
#pragma unroll
    for (int kk = 0; kk < 16; ++kk) {
      const float4 a = *(const float4*)&As[kk][ty * 4];
      const float4 w = *(const float4*)&Ws[kk][tx * 4];
      const float av[4] = {a.x, a.y, a.z, a.w};
      const float wv2[4] = {w.x, w.y, w.z, w.w};
#pragma unroll
      for (int ii = 0; ii < 4; ++ii)
#pragma unroll
        for (int jj = 0; jj < 4; ++jj)
          acc[ii][jj] = fmaf(av[ii], wv2[jj], acc[ii][jj]);
    }
    __syncthreads();
  }
  const float4 b4 = *(const float4*)(bias + n0 + tx * 4);
  const float bb[4] = {b4.x, b4.y, b4.z, b4.w};
#pragma unroll
  for (int ii = 0; ii < 4; ++ii) {
    const int gr = m0 + ty * 4 + ii;
    if (gr < M) {
      float4 o;
      o.x = acc[ii][0] + bb[0];
      o.y = acc[ii][1] + bb[1];
      o.z = acc[ii][2] + bb[2];
      o.w = acc[ii][3] + bb[3];
      if (relu) {
        o.x = fmaxf(o.x, 0.f); o.y = fmaxf(o.y, 0.f);
        o.z = fmaxf(o.z, 0.f); o.w = fmaxf(o.w, 0.f);
      }
      *(float4*)(Y + (size_t)gr * N + n0 + tx * 4) = o;
    }
  }
}

// ---------------- self-attention: MFMA flash (swapped QK^T), bf16 ----------------
#define QB 64
#define KB 64
#define KP 40   // Ks / P pitch (ushort)
#define VP 72   // Vt pitch (ushort)
__global__ __launch_bounds__(256) void attn_mfma_kernel(
    const float* __restrict__ QK, const float* __restrict__ V,
    float* __restrict__ O)
{
  __shared__ ushort Ks[KB * KP];
  __shared__ ushort Vt[DH_ * VP];
  __shared__ ushort Pl[4][16 * KP];
  const int tid  = threadIdx.x;
  const int lane = tid & 63;
  const int w    = tid >> 6;
  const int bh = blockIdx.y;
  const int h  = bh & (HEADS_ - 1);
  const int b  = bh >> 3;
  const int q0 = blockIdx.x * QB;
  const int lq = lane & 15;
  const int lg = lane >> 4;
  const float scale = 0.17677669529663687f;
  const f32x4 zero4 = {0.f, 0.f, 0.f, 0.f};

  bf16x8 qf;
  {
    int qg = q0 + w * 16 + lq; if (qg > LQ_ - 1) qg = LQ_ - 1;
    const float* qp = QK + ((size_t)qg * B_ + b) * 512 + h * DH_ + lg * 8;
    const float4 a = *(const float4*)qp;
    const float4 c = *(const float4*)(qp + 4);
    ushort t[8] __attribute__((aligned(16)));
    t[0]=f2bf(a.x*scale); t[1]=f2bf(a.y*scale); t[2]=f2bf(a.z*scale); t[3]=f2bf(a.w*scale);
    t[4]=f2bf(c.x*scale); t[5]=f2bf(c.y*scale); t[6]=f2bf(c.z*scale); t[7]=f2bf(c.w*scale);
    qf = *(const bf16x8*)t;
  }

  float mrow = -1e30f, srow = 0.f;
  f32x4 oacc[2]; oacc[0] = zero4; oacc[1] = zero4;

  const int nkt = (LQ_ + KB - 1) / KB;   // 15
  for (int t = 0; t < nkt; ++t) {
    const int k0 = t * KB;
    const int klen = (LQ_ - k0) < KB ? (LQ_ - k0) : KB;
    if (t) __syncthreads();
    {
      const int kk  = tid >> 2;
      const int dh0 = (tid & 3) * 8;
      ushort kb[8] __attribute__((aligned(16)));
      ushort vb[8];
      if (kk < klen) {
        const size_t row = (size_t)(k0 + kk) * B_ + b;
        const float* kp = QK + row * 512 + 256 + h * DH_ + dh0;
        const float* vp = V  + row * 256 + h * DH_ + dh0;
        const float4 k1 = *(const float4*)kp;
        const float4 k2 = *(const float4*)(kp + 4);
        const float4 v1 = *(const float4*)vp;
        const float4 v2 = *(const float4*)(vp + 4);
        kb[0]=f2bf(k1.x); kb[1]=f2bf(k1.y); kb[2]=f2bf(k1.z); kb[3]=f2bf(k1.w);
        kb[4]=f2bf(k2.x); kb[5]=f2bf(k2.y); kb[6]=f2bf(k2.z); kb[7]=f2bf(k2.w);
        vb[0]=f2bf(v1.x); vb[1]=f2bf(v1.y); vb[2]=f2bf(v1.z); vb[3]=f2bf(v1.w);
        vb[4]=f2bf(v2.x); vb[5]=f2bf(v2.y); vb[6]=f2bf(v2.z); vb[7]=f2bf(v2.w);
      } else {
#pragma unroll
        for (int j = 0; j < 8; ++j) { kb[j] = 0; vb[j] = 0; }
      }
      *(bf16x8*)&Ks[kk * KP + dh0] = *(const bf16x8*)kb;
#pragma unroll
      for (int j = 0; j < 8; ++j) Vt[(dh0 + j) * VP + kk] = vb[j];
    }
    __syncthreads();

    f32x4 sc[4];
#pragma unroll
    for (int j = 0; j < 4; ++j) {
      const bf16x8 kf = *(const bf16x8*)&Ks[(j * 16 + lq) * KP + lg * 8];
      sc[j] = __builtin_amdgcn_mfma_f32_16x16x32_bf16(kf, qf, zero4, 0, 0, 0);
    }
    if (klen < KB) {
#pragma unroll
      for (int j = 0; j < 4; ++j)
#pragma unroll
        for (int r = 0; r < 4; ++r)
          if (j * 16 + lg * 4 + r >= klen) sc[j][r] = -1e30f;
    }
    float tmax = -1e30f;
#pragma unroll
    for (int j = 0; j < 4; ++j)
#pragma unroll
      for (int r = 0; r < 4; ++r) tmax = fmaxf(tmax, sc[j][r]);
    tmax = fmaxf(tmax, __shfl_xor(tmax, 16, 64));
    tmax = fmaxf(tmax, __shfl_xor(tmax, 32, 64));
    const float mnew = fmaxf(mrow, tmax);
    const float cfac = __expf(mrow - mnew);
    mrow = mnew;
    float tsum = 0.f;
#pragma unroll
    for (int j = 0; j < 4; ++j)
#pragma unroll
      for (int r = 0; r < 4; ++r) {
        const float p = __expf(sc[j][r] - mnew);
        sc[j][r] = p; tsum += p;
      }
    tsum += __shfl_xor(tsum, 16, 64);
    tsum += __shfl_xor(tsum, 32, 64);
    srow = srow * cfac + tsum;
#pragma unroll
    for (int j = 0; j < 4; ++j) {
      const uint lo = (uint)f2bf(sc[j][0]) | ((uint)f2bf(sc[j][1]) << 16);
      const uint hi = (uint)f2bf(sc[j][2]) | ((uint)f2bf(sc[j][3]) << 16);
      *(uint*)&Pl[w][lq * KP + j * 16 + lg * 4]     = lo;
      *(uint*)&Pl[w][lq * KP + j * 16 + lg * 4 + 2] = hi;
    }
    float crow[4];
#pragma unroll
    for (int r = 0; r < 4; ++r) crow[r] = __shfl(cfac, lg * 4 + r, 64);
#pragma unroll
    for (int nt = 0; nt < 2; ++nt)
#pragma unroll
      for (int r = 0; r < 4; ++r) oacc[nt][r] *= crow[r];
#pragma unroll
    for (int ks = 0; ks < 2; ++ks) {
      const bf16x8 pf = *(const bf16x8*)&Pl[w][lq * KP + ks * 32 + lg * 8];
#pragma unroll
      for (int nt = 0; nt < 2; ++nt) {
        const bf16x8 vf = *(const bf16x8*)&Vt[(nt * 16 + lq) * VP + ks * 32 + lg * 8];
        oacc[nt] = __builtin_amdgcn_mfma_f32_16x16x32_bf16(pf, vf, oacc[nt], 0, 0, 0);
      }
    }
  }
  float sinv[4];
#pragma unroll
  for (int r = 0; r < 4; ++r) {
    const float sr = __shfl(srow, lg * 4 + r, 64);
    sinv[r] = 1.f / sr;
  }
#pragma unroll
  for (int r = 0; r < 4; ++r) {
    const int qg = q0 + w * 16 + lg * 4 + r;
    if (qg < LQ_) {
      float* op = O + ((size_t)qg * B_ + b) * 256 + h * DH_;
      op[lq]      = oacc[0][r] * sinv[r];
      op[16 + lq] = oacc[1][r] * sinv[r];
    }
  }
}

// ---------------- residual + LayerNorm: Y = LN(X + R) * g + b ----------------
__global__ __launch_bounds__(256) void ln_kernel(
    const float* __restrict__ X, const float* __restrict__ R,
    const float* __restrict__ g, const float* __restrict__ be,
    float* __restrict__ Y)
{
  const int row = blockIdx.x;
  const int t = threadIdx.x;
  const size_t idx = (size_t)row * D_ + t;
  const float v = X[idx] + R[idx];
  __shared__ float red[4];
  const int wid = t >> 6, lane = t & 63;

  float sum = v;
#pragma unroll
  for (int o = 32; o > 0; o >>= 1) sum += __shfl_xor(sum, o, 64);
  if (lane == 0) red[wid] = sum;
  __syncthreads();
  const float mean = (red[0] + red[1] + red[2] + red[3]) * (1.f / D_);
  const float d = v - mean;
  float sq = d * d;
#pragma unroll
  for (int o = 32; o > 0; o >>= 1) sq += __shfl_xor(sq, o, 64);
  __syncthreads();
  if (lane == 0) red[wid] = sq;
  __syncthreads();
  const float var = (red[0] + red[1] + red[2] + red[3]) * (1.f / D_);
  Y[idx] = d * rsqrtf(var + 1e-5f) * g[t] + be[t];
}

// ---------------- MSDeformAttn sampling (bf16 value; 4 threads per (q,b,h)) ----------------
__global__ __launch_bounds__(256) void msdeform_kernel(
    const float* __restrict__ refp, const float* __restrict__ offb,
    const float* __restrict__ awb, const ushort* __restrict__ value,
    float* __restrict__ out)
{
  const int t  = blockIdx.x * 256 + threadIdx.x;   // < MQ*HEADS_*4
  const int dq = t & 3;            // dh quarter: 8 floats
  const int h  = (t >> 2) & 7;
  const int u  = t >> 5;           // b*LQ_ + q
  const int b  = u / LQ_;
  const int q  = u - b * LQ_;
  const int r  = q * B_ + b;

  float aw[LVLS_ * PTS_];
  const float* ap = awb + (size_t)r * 128 + h * 16;
  float m = -1e30f;
#pragma unroll
  for (int i = 0; i < 16; ++i) { aw[i] = ap[i]; m = fmaxf(m, aw[i]); }
  float s = 0.f;
#pragma unroll
  for (int i = 0; i < 16; ++i) { aw[i] = __expf(aw[i] - m); s += aw[i]; }
  const float inv = 1.f / s;
#pragma unroll
  for (int i = 0; i < 16; ++i) aw[i] *= inv;

  float o[8] = {};
  const int HH[4] = {100, 50, 25, 13};
  const int WW[4] = {100, 50, 25, 13};
  const int ST[4] = {0, 10000, 12500, 13125};
  const float* orow = offb + (size_t)r * 256 + h * (LVLS_ * PTS_ * 2);
  const int dh0 = h * DH_ + dq * 8;

  for (int l = 0; l < LVLS_; ++l) {
    const float4 rf = *(const float4*)(refp + (((size_t)q * B_ + b) * LVLS_ + l) * 4);
    const int W_ = WW[l], H_ = HH[l], s0 = ST[l];
    for (int p = 0; p < PTS_; ++p) {
      const float ox = orow[(l * PTS_ + p) * 2 + 0];
      const float oy = orow[(l * PTS_ + p) * 2 + 1];
      const float lx = rf.x + ox * 0.125f * rf.z;
      const float ly = rf.y + oy * 0.125f * rf.w;
      const float x = lx * W_ - 0.5f;
      const float y = ly * H_ - 0.5f;
      const float x0f = floorf(x), y0f = floorf(y);
      const float wx = x - x0f, wy = y - y0f;
      const int x0 = (int)x0f, y0 = (int)y0f;
      const float a = aw[l * PTS_ + p];
      const float cw[4] = {(1.f - wx) * (1.f - wy) * a, wx * (1.f - wy) * a,
                           (1.f - wx) * wy * a,         wx * wy * a};
      const int cx[4] = {x0, x0 + 1, x0, x0 + 1};
      const int cy[4] = {y0, y0, y0 + 1, y0 + 1};
#pragma unroll
      for (int c = 0; c < 4; ++c) {
        const int xi = cx[c], yi = cy[c];
        if (xi >= 0 && xi < W_ && yi >= 0 && yi < H_) {
          const ushort* vp = value + ((size_t)(s0 + yi * W_ + xi) * B_ + b) * 256 + dh0;
          const float w = cw[c];
          const bf16x8 vv = *(const bf16x8*)vp;   // 16 B
#pragma unroll
          for (int j = 0; j < 8; ++j)
            o[j] = fmaf(w, bf2f(((const ushort*)&vv)[j]), o[j]);
        }
      }
    }
  }
  float* op = out + (size_t)r * 256 + dh0;
  float4 x1; x1.x = o[0]; x1.y = o[1]; x1.z = o[2]; x1.w = o[3];
  float4 x2; x2.x = o[4]; x2.y = o[5]; x2.z = o[6]; x2.w = o[7];
  *(float4*)op = x1;
  *(float4*)(op + 4) = x2;
}

extern "C" void kernel_launch(void* const* d_in, const int* in_sizes, int n_in,
                              void* d_out, int out_size, void* d_ws, size_t ws_size,
                              hipStream_t stream) {
  const float* tgt       = (const float*)d_in[0];
  const float* pos       = (const float*)d_in[1];
  const float* refp      = (const float*)d_in[2];
  const float* memory    = (const float*)d_in[3];
  const float* in_proj_w = (const float*)d_in[6];
  const float* in_proj_b = (const float*)d_in[7];
  const float* sa_out_w  = (const float*)d_in[8];
  const float* sa_out_b  = (const float*)d_in[9];
  const float* off_w     = (const float*)d_in[10];
  const float* off_b     = (const float*)d_in[11];
  const float* aw_w      = (const float*)d_in[12];
  const float* aw_b      = (const float*)d_in[13];
  const float* val_w     = (const float*)d_in[14];
  const float* val_b     = (const float*)d_in[15];
  const float* ca_out_w  = (const float*)d_in[16];
  const float* ca_out_b  = (const float*)d_in[17];
  const float* lin1_w    = (const float*)d_in[18];
  const float* lin1_b    = (const float*)d_in[19];
  const float* lin2_w    = (const float*)d_in[20];
  const float* lin2_b    = (const float*)d_in[21];
  const float* n1g = (const float*)d_in[22];
  const float* n1b = (const float*)d_in[23];
  const float* n2g = (const float*)d_in[24];
  const float* n2b = (const float*)d_in[25];
  const float* n3g = (const float*)d_in[26];
  const float* n3b = (const float*)d_in[27];

  float* ws = (float*)d_ws;
  float* QK    = ws;                               // MQ*512
  float* Vb    = QK   + (size_t)MQ * 512;          // MQ*256
  float* Cb    = Vb   + (size_t)MQ * 256;          // MQ*256
  float* Db    = Cb   + (size_t)MQ * 256;          // MQ*256
  float* tgt1  = Db   + (size_t)MQ * 256;          // MQ*256
  float* tgt2  = tgt1 + (size_t)MQ * 256;          // MQ*256
  float* big   = tgt2 + (size_t)MQ * 256;          // max(MV*128, MQ*1024) floats
  ushort* value = (ushort*)big;                    // MV*256 bf16
  float* mid   = big;   // FFN mid aliases value region (disjoint lifetimes)

  const dim3 blk(256);
  const int gy_q = (MQ + 63) / 64;        // 225
  const int gy_q128 = (MQ + 127) / 128;   // 113
  const int gy_v128 = (MV + 127) / 128;   // 1662
  const int qtiles = (LQ_ + QB - 1) / QB; // 15

  // 1) Q,K projections (input tgt+pos), N=512 — bf16 MFMA
  gemm_bf16_kernel<<<dim3(4, gy_q128), blk, 0, stream>>>(tgt, pos, in_proj_w, in_proj_b, QK, MQ, 512, D_, 0, 0);
  // 2) V projection (input tgt), N=256 — bf16 MFMA
  gemm_bf16_kernel<<<dim3(2, gy_q128), blk, 0, stream>>>(tgt, nullptr, in_proj_w + 512 * D_, in_proj_b + 512, Vb, MQ, 256, D_, 0, 0);
  // 3) self-attention — bf16 MFMA flash
  attn_mfma_kernel<<<dim3(qtiles, B_ * HEADS_), blk, 0, stream>>>(QK, Vb, Cb);
  // 4) SA out proj — bf16 MFMA
  gemm_bf16_kernel<<<dim3(2, gy_q128), blk, 0, stream>>>(Cb, nullptr, sa_out_w, sa_out_b, Db, MQ, 256, D_, 0, 0);
  // 5) tgt1 = LN(tgt + sa; norm2)
  ln_kernel<<<MQ, blk, 0, stream>>>(tgt, Db, n2g, n2b, tgt1);
  // 6) value projection over memory — bf16 MFMA, bf16 output
  gemm_bf16_kernel<<<dim3(2, gy_v128), blk, 0, stream>>>(memory, nullptr, val_w, val_b, (float*)value, MV, 256, D_, 0, 1);
  // 7) sampling offsets (input tgt1+pos) — f32 for position precision
  gemm_bias_kernel<<<dim3(4, gy_q), blk, 0, stream>>>(tgt1, pos, off_w, off_b, QK, MQ, 256, D_, 0);
  // 8) attention-weight logits — f32
  gemm_bias_kernel<<<dim3(2, gy_q), blk, 0, stream>>>(tgt1, pos, aw_w, aw_b, Vb, MQ, 128, D_, 0);
  // 9) deformable sampling -> Cb  (bf16 value gather)
  msdeform_kernel<<<(MQ * HEADS_ * 4 + 255) / 256, blk, 0, stream>>>(refp, QK, Vb, value, Cb);
  // 10) CA out proj — bf16 MFMA
  gemm_bf16_kernel<<<dim3(2, gy_q128), blk, 0, stream>>>(Cb, nullptr, ca_out_w, ca_out_b, Db, MQ, 256, D_, 0, 0);
  // 11) tgt2 = LN(tgt1 + ca; norm1)
  ln_kernel<<<MQ, blk, 0, stream>>>(tgt1, Db, n1g, n1b, tgt2);
  // 12) FFN lin1 + relu -> mid — bf16 MFMA
  gemm_bf16_kernel<<<dim3(8, gy_q128), blk, 0, stream>>>(tgt2, nullptr, lin1_w, lin1_b, mid, MQ, DFF_, D_, 1, 0);
  // 13) FFN lin2 -> Db — bf16 MFMA (K=1024)
  gemm_bf16_kernel<<<dim3(2, gy_q128), blk, 0, stream>>>(mid, nullptr, lin2_w, lin2_b, Db, MQ, 256, DFF_, 0, 0);
  // 14) out = LN(tgt2 + ffn; norm3)
  ln_kernel<<<MQ, blk, 0, stream>>>(tgt2, Db, n3g, n3b, (float*)d_out);
}

// Round 8
// 556.780 us; speedup vs baseline: 1.3701x; 1.3701x over previous
//
#include <hip/hip_runtime.h>
#include <hip/hip_bf16.h>
#include <math.h>

#define D_ 256
#define HEADS_ 8
#define DH_ 32
#define LVLS_ 4
#define PTS_ 4
#define DFF_ 1024
#define LQ_ 900
#define B_ 16
#define S_ 13294
#define MQ (LQ_*B_)      // 14400
#define MV (S_*B_)       // 212704

typedef __attribute__((ext_vector_type(4))) float f32x4;
typedef __attribute__((ext_vector_type(8))) short bf16x8;

static __device__ inline ushort f2bf(float f) {
  __hip_bfloat16 h = __float2bfloat16(f);   // RNE
  union { __hip_bfloat16 h; ushort u; } c; c.h = h;
  return c.u;
}
static __device__ inline float bf2f(ushort u) {
  union { float f; uint u; } c; c.u = (uint)u << 16; return c.f;
}

#define GP 40   // LDS pitch in ushorts (80 B rows)

// ---------------- bf16-MFMA GEMM, 128x128 tile (for large M) ----------------
// Y = act((A [+ X2]) @ W^T + bias). A,X2:[M,K] f32; W:[N,K] f32; Y f32 or bf16.
// N % 128 == 0, K % 32 == 0. Staged LDS + depth-1 register prefetch (best
// measured variant: R5, 145 us on value proj).
__global__ __launch_bounds__(256) void gemm_bf16_kernel(
    const float* __restrict__ A, const float* __restrict__ X2,
    const float* __restrict__ Wm, const float* __restrict__ bias,
    float* __restrict__ Y, int M, int N, int K, int relu, int outbf)
{
  __shared__ ushort As[128 * GP];   // 10 KB
  __shared__ ushort Ws[128 * GP];   // 10 KB
  const int tid  = threadIdx.x;
  const int lane = tid & 63;
  const int wid  = tid >> 6;
  const int wr = wid >> 1, wc = wid & 1;
  const int fr = lane & 15;
  const int fk = (lane >> 4) << 3;
  const int m0 = blockIdx.y * 128, n0 = blockIdx.x * 128;

  f32x4 acc[4][4];
  const f32x4 zero = {0.f, 0.f, 0.f, 0.f};
#pragma unroll
  for (int i = 0; i < 4; ++i)
#pragma unroll
    for (int j = 0; j < 4; ++j) acc[i][j] = zero;

  const int srow = tid >> 1;
  const int skh  = (tid & 1) << 4;
  int agr = m0 + srow; if (agr > M - 1) agr = M - 1;
  const float* apb = A  + (size_t)agr * K + skh;
  const float* xpb = X2 ? (X2 + (size_t)agr * K + skh) : nullptr;
  const float* wpb = Wm + (size_t)(n0 + srow) * K + skh;

  // preload k-tile 0
  float4 pa[4], pw[4];
#pragma unroll
  for (int i2 = 0; i2 < 4; ++i2) {
    pa[i2] = *(const float4*)(apb + i2 * 4);
    pw[i2] = *(const float4*)(wpb + i2 * 4);
  }
  if (xpb) {
#pragma unroll
    for (int i2 = 0; i2 < 4; ++i2) {
      const float4 u = *(const float4*)(xpb + i2 * 4);
      pa[i2].x += u.x; pa[i2].y += u.y; pa[i2].z += u.z; pa[i2].w += u.w;
    }
  }

  for (int k0 = 0; k0 < K; k0 += 32) {
    if (k0) __syncthreads();
    ushort tmp[16] __attribute__((aligned(16)));
#pragma unroll
    for (int i2 = 0; i2 < 4; ++i2) {
      tmp[i2*4+0] = f2bf(pa[i2].x); tmp[i2*4+1] = f2bf(pa[i2].y);
      tmp[i2*4+2] = f2bf(pa[i2].z); tmp[i2*4+3] = f2bf(pa[i2].w);
    }
    *(bf16x8*)&As[srow*GP + skh]     = *(const bf16x8*)&tmp[0];
    *(bf16x8*)&As[srow*GP + skh + 8] = *(const bf16x8*)&tmp[8];
#pragma unroll
    for (int i2 = 0; i2 < 4; ++i2) {
      tmp[i2*4+0] = f2bf(pw[i2].x); tmp[i2*4+1] = f2bf(pw[i2].y);
      tmp[i2*4+2] = f2bf(pw[i2].z); tmp[i2*4+3] = f2bf(pw[i2].w);
    }
    *(bf16x8*)&Ws[srow*GP + skh]     = *(const bf16x8*)&tmp[0];
    *(bf16x8*)&Ws[srow*GP + skh + 8] = *(const bf16x8*)&tmp[8];
    // issue next k-tile loads (in flight during MFMA phase)
    if (k0 + 32 < K) {
      const float* ap = apb + k0 + 32;
      const float* wp = wpb + k0 + 32;
#pragma unroll
      for (int i2 = 0; i2 < 4; ++i2) {
        pa[i2] = *(const float4*)(ap + i2 * 4);
        pw[i2] = *(const float4*)(wp + i2 * 4);
      }
      if (xpb) {
        const float* xp = xpb + k0 + 32;
#pragma unroll
        for (int i2 = 0; i2 < 4; ++i2) {
          const float4 u = *(const float4*)(xp + i2 * 4);
          pa[i2].x += u.x; pa[i2].y += u.y; pa[i2].z += u.z; pa[i2].w += u.w;
        }
      }
    }
    __syncthreads();

    bf16x8 ar[4], br[4];
#pragma unroll
    for (int i = 0; i < 4; ++i)
      ar[i] = *(const bf16x8*)&As[(wr*64 + i*16 + fr)*GP + fk];
#pragma unroll
    for (int j = 0; j < 4; ++j)
      br[j] = *(const bf16x8*)&Ws[(wc*64 + j*16 + fr)*GP + fk];
#pragma unroll
    for (int i = 0; i < 4; ++i)
#pragma unroll
      for (int j = 0; j < 4; ++j)
        acc[i][j] = __builtin_amdgcn_mfma_f32_16x16x32_bf16(ar[i], br[j], acc[i][j], 0, 0, 0);
  }

  const int gcolbase = n0 + wc * 64 + fr;
  float bias4[4];
#pragma unroll
  for (int j = 0; j < 4; ++j) bias4[j] = bias[gcolbase + j * 16];
#pragma unroll
  for (int i = 0; i < 4; ++i) {
    const int rb = m0 + wr * 64 + i * 16 + (lane >> 4) * 4;
#pragma unroll
    for (int r = 0; r < 4; ++r) {
      const int grow = rb + r;
      if (grow < M) {
#pragma unroll
        for (int j = 0; j < 4; ++j) {
          float v = acc[i][j][r] + bias4[j];
          if (relu) v = fmaxf(v, 0.f);
          if (outbf) ((ushort*)Y)[(size_t)grow * N + gcolbase + j * 16] = f2bf(v);
          else       Y[(size_t)grow * N + gcolbase + j * 16] = v;
        }
      }
    }
  }
}

// ---------------- bf16-MFMA GEMM, 64x64 tile (for M=14400 shapes) ----------------
// Same structure, 4x the blocks of a 128-tile launch -> occupancy for small grids.
// N % 64 == 0, K % 32 == 0, M % 64 == 0 assumed tail-free (guarded anyway).
__global__ __launch_bounds__(256) void gemm_bf16_64(
    const float* __restrict__ A, const float* __restrict__ X2,
    const float* __restrict__ Wm, const float* __restrict__ bias,
    float* __restrict__ Y, int M, int N, int K, int relu)
{
  __shared__ ushort As[64 * GP];   // 5 KB
  __shared__ ushort Ws[64 * GP];   // 5 KB
  const int tid  = threadIdx.x;
  const int lane = tid & 63;
  const int wid  = tid >> 6;
  const int wr = wid >> 1, wc = wid & 1;     // wave quadrant in 2x2 (32x32 each)
  const int fr = lane & 15;
  const int fk = (lane >> 4) << 3;
  const int m0 = blockIdx.y * 64, n0 = blockIdx.x * 64;

  f32x4 acc[2][2];
  const f32x4 zero = {0.f, 0.f, 0.f, 0.f};
#pragma unroll
  for (int i = 0; i < 2; ++i)
#pragma unroll
    for (int j = 0; j < 2; ++j) acc[i][j] = zero;

  // staging: thread t owns row t>>1 of the combined [A(64) | W(64)] tile,
  // k-half (t&1)*16 (16 floats -> 16 bf16).
  const int srow = tid >> 1;          // 0..127
  const int skh  = (tid & 1) << 4;    // 0 or 16
  const bool isA = srow < 64;
  const float* src;
  const float* src2 = nullptr;
  ushort* dst;
  if (isA) {
    int gr = m0 + srow; if (gr > M - 1) gr = M - 1;
    src = A + (size_t)gr * K + skh;
    if (X2) src2 = X2 + (size_t)gr * K + skh;
    dst = &As[srow * GP + skh];
  } else {
    src = Wm + (size_t)(n0 + srow - 64) * K + skh;
    dst = &Ws[(srow - 64) * GP + skh];
  }

  float4 pd[4];
#pragma unroll
  for (int i2 = 0; i2 < 4; ++i2) pd[i2] = *(const float4*)(src + i2 * 4);
  if (src2) {
#pragma unroll
    for (int i2 = 0; i2 < 4; ++i2) {
      const float4 u = *(const float4*)(src2 + i2 * 4);
      pd[i2].x += u.x; pd[i2].y += u.y; pd[i2].z += u.z; pd[i2].w += u.w;
    }
  }

  for (int k0 = 0; k0 < K; k0 += 32) {
    if (k0) __syncthreads();
    ushort tmp[16] __attribute__((aligned(16)));
#pragma unroll
    for (int i2 = 0; i2 < 4; ++i2) {
      tmp[i2*4+0] = f2bf(pd[i2].x); tmp[i2*4+1] = f2bf(pd[i2].y);
      tmp[i2*4+2] = f2bf(pd[i2].z); tmp[i2*4+3] = f2bf(pd[i2].w);
    }
    *(bf16x8*)(dst)     = *(const bf16x8*)&tmp[0];
    *(bf16x8*)(dst + 8) = *(const bf16x8*)&tmp[8];
    if (k0 + 32 < K) {
      const float* s = src + k0 + 32;
#pragma unroll
      for (int i2 = 0; i2 < 4; ++i2) pd[i2] = *(const float4*)(s + i2 * 4);
      if (src2) {
        const float* s2 = src2 + k0 + 32;
#pragma unroll
        for (int i2 = 0; i2 < 4; ++i2) {
          const float4 u = *(const float4*)(s2 + i2 * 4);
          pd[i2].x += u.x; pd[i2].y += u.y; pd[i2].z += u.z; pd[i2].w += u.w;
        }
      }
    }
    __syncthreads();

    bf16x8 af[2], bf[2];
#pragma unroll
    for (int i = 0; i < 2; ++i)
      af[i] = *(const bf16x8*)&As[(wr*32 + i*16 + fr)*GP + fk];
#pragma unroll
    for (int j = 0; j < 2; ++j)
      bf[j] = *(const bf16x8*)&Ws[(wc*32 + j*16 + fr)*GP + fk];
#pragma unroll
    for (int i = 0; i < 2; ++i)
#pragma unroll
      for (int j = 0; j < 2; ++j)
        acc[i][j] = __builtin_amdgcn_mfma_f32_16x16x32_bf16(af[i], bf[j], acc[i][j], 0, 0, 0);
  }

  const int gcolbase = n0 + wc * 32 + fr;
  float bias2[2];
#pragma unroll
  for (int j = 0; j < 2; ++j) bias2[j] = bias[gcolbase + j * 16];
#pragma unroll
  for (int i = 0; i < 2; ++i) {
    const int rb = m0 + wr * 32 + i * 16 + (lane >> 4) * 4;
#pragma unroll
    for (int r = 0; r < 4; ++r) {
      const int grow = rb + r;
      if (grow < M) {
#pragma unroll
        for (int j = 0; j < 2; ++j) {
          float v = acc[i][j][r] + bias2[j];
          if (relu) v = fmaxf(v, 0.f);
          Y[(size_t)grow * N + gcolbase + j * 16] = v;
        }
      }
    }
  }
}

// ---------------- generic f32 GEMM: Y = act((X1 [+ X2]) @ W^T + bias) ----------------
__global__ __launch_bounds__(256) void gemm_bias_kernel(
    const float* __restrict__ X1, const float* __restrict__ X2,
    const float* __restrict__ W, const float* __restrict__ bias,
    float* __restrict__ Y, int M, int N, int K, int relu)
{
  __shared__ float As[16][64];
  __shared__ float Ws[16][64];
  const int tid = threadIdx.x;
  const int tx = tid & 15, ty = tid >> 4;
  const int m0 = blockIdx.y * 64, n0 = blockIdx.x * 64;
  float acc[4][4] = {};
  for (int k0 = 0; k0 < K; k0 += 16) {
    const int i   = tid * 4;
    const int row = i >> 4;
    const int col = i & 15;
    const int gr  = m0 + row;
    float4 v = make_float4(0.f, 0.f, 0.f, 0.f);
    if (gr < M) {
      v = *(const float4*)(X1 + (size_t)gr * K + k0 + col);
      if (X2) {
        float4 u = *(const float4*)(X2 + (size_t)gr * K + k0 + col);
        v.x += u.x; v.y += u.y; v.z += u.z; v.w += u.w;
      }
    }
    As[col+0][row] = v.x; As[col+1][row] = v.y; As[col+2][row] = v.z; As[col+3][row] = v.w;
    const float4 wv = *(const float4*)(W + (size_t)(n0 + row) * K + k0 + col);
    Ws[col+0][row] = wv.x; Ws[col+1][row] = wv.y; Ws[col+2][row] = wv.z; Ws[col+3][row] = wv.w;
    __syncthreads();
#pragma unroll
    for (int kk = 0; kk < 16; ++kk) {
      const float4 a = *(const float4*)&As[kk][ty * 4];
      const float4 w = *(const float4*)&Ws[kk][tx * 4];
      const float av[4] = {a.x, a.y, a.z, a.w};
      const float wv2[4] = {w.x, w.y, w.z, w.w};
#pragma unroll
      for (int ii = 0; ii < 4; ++ii)
#pragma unroll
        for (int jj = 0; jj < 4; ++jj)
          acc[ii][jj] = fmaf(av[ii], wv2[jj], acc[ii][jj]);
    }
    __syncthreads();
  }
  const float4 b4 = *(const float4*)(bias + n0 + tx * 4);
  const float bb[4] = {b4.x, b4.y, b4.z, b4.w};
#pragma unroll
  for (int ii = 0; ii < 4; ++ii) {
    const int gr = m0 + ty * 4 + ii;
    if (gr < M) {
      float4 o;
      o.x = acc[ii][0] + bb[0];
      o.y = acc[ii][1] + bb[1];
      o.z = acc[ii][2] + bb[2];
      o.w = acc[ii][3] + bb[3];
      if (relu) {
        o.x = fmaxf(o.x, 0.f); o.y = fmaxf(o.y, 0.f);
        o.z = fmaxf(o.z, 0.f); o.w = fmaxf(o.w, 0.f);
      }
      *(float4*)(Y + (size_t)gr * N + n0 + tx * 4) = o;
    }
  }
}

// ---------------- self-attention: MFMA flash (swapped QK^T), bf16 ----------------
#define QB 64
#define KB 64
#define KP 40   // Ks / P pitch (ushort)
#define VP 72   // Vt pitch (ushort)
__global__ __launch_bounds__(256) void attn_mfma_kernel(
    const float* __restrict__ QK, const float* __restrict__ V,
    float* __restrict__ O)
{
  __shared__ ushort Ks[KB * KP];
  __shared__ ushort Vt[DH_ * VP];
  __shared__ ushort Pl[4][16 * KP];
  const int tid  = threadIdx.x;
  const int lane = tid & 63;
  const int w    = tid >> 6;
  const int bh = blockIdx.y;
  const int h  = bh & (HEADS_ - 1);
  const int b  = bh >> 3;
  const int q0 = blockIdx.x * QB;
  const int lq = lane & 15;
  const int lg = lane >> 4;
  const float scale = 0.17677669529663687f;
  const f32x4 zero4 = {0.f, 0.f, 0.f, 0.f};

  bf16x8 qf;
  {
    int qg = q0 + w * 16 + lq; if (qg > LQ_ - 1) qg = LQ_ - 1;
    const float* qp = QK + ((size_t)qg * B_ + b) * 512 + h * DH_ + lg * 8;
    const float4 a = *(const float4*)qp;
    const float4 c = *(const float4*)(qp + 4);
    ushort t[8] __attribute__((aligned(16)));
    t[0]=f2bf(a.x*scale); t[1]=f2bf(a.y*scale); t[2]=f2bf(a.z*scale); t[3]=f2bf(a.w*scale);
    t[4]=f2bf(c.x*scale); t[5]=f2bf(c.y*scale); t[6]=f2bf(c.z*scale); t[7]=f2bf(c.w*scale);
    qf = *(const bf16x8*)t;
  }

  float mrow = -1e30f, srow = 0.f;
  f32x4 oacc[2]; oacc[0] = zero4; oacc[1] = zero4;

  const int nkt = (LQ_ + KB - 1) / KB;   // 15
  for (int t = 0; t < nkt; ++t) {
    const int k0 = t * KB;
    const int klen = (LQ_ - k0) < KB ? (LQ_ - k0) : KB;
    if (t) __syncthreads();
    {
      const int kk  = tid >> 2;
      const int dh0 = (tid & 3) * 8;
      ushort kb[8] __attribute__((aligned(16)));
      ushort vb[8];
      if (kk < klen) {
        const size_t row = (size_t)(k0 + kk) * B_ + b;
        const float* kp = QK + row * 512 + 256 + h * DH_ + dh0;
        const float* vp = V  + row * 256 + h * DH_ + dh0;
        const float4 k1 = *(const float4*)kp;
        const float4 k2 = *(const float4*)(kp + 4);
        const float4 v1 = *(const float4*)vp;
        const float4 v2 = *(const float4*)(vp + 4);
        kb[0]=f2bf(k1.x); kb[1]=f2bf(k1.y); kb[2]=f2bf(k1.z); kb[3]=f2bf(k1.w);
        kb[4]=f2bf(k2.x); kb[5]=f2bf(k2.y); kb[6]=f2bf(k2.z); kb[7]=f2bf(k2.w);
        vb[0]=f2bf(v1.x); vb[1]=f2bf(v1.y); vb[2]=f2bf(v1.z); vb[3]=f2bf(v1.w);
        vb[4]=f2bf(v2.x); vb[5]=f2bf(v2.y); vb[6]=f2bf(v2.z); vb[7]=f2bf(v2.w);
      } else {
#pragma unroll
        for (int j = 0; j < 8; ++j) { kb[j] = 0; vb[j] = 0; }
      }
      *(bf16x8*)&Ks[kk * KP + dh0] = *(const bf16x8*)kb;
#pragma unroll
      for (int j = 0; j < 8; ++j) Vt[(dh0 + j) * VP + kk] = vb[j];
    }
    __syncthreads();

    f32x4 sc[4];
#pragma unroll
    for (int j = 0; j < 4; ++j) {
      const bf16x8 kf = *(const bf16x8*)&Ks[(j * 16 + lq) * KP + lg * 8];
      sc[j] = __builtin_amdgcn_mfma_f32_16x16x32_bf16(kf, qf, zero4, 0, 0, 0);
    }
    if (klen < KB) {
#pragma unroll
      for (int j = 0; j < 4; ++j)
#pragma unroll
        for (int r = 0; r < 4; ++r)
          if (j * 16 + lg * 4 + r >= klen) sc[j][r] = -1e30f;
    }
    float tmax = -1e30f;
#pragma unroll
    for (int j = 0; j < 4; ++j)
#pragma unroll
      for (int r = 0; r < 4; ++r) tmax = fmaxf(tmax, sc[j][r]);
    tmax = fmaxf(tmax, __shfl_xor(tmax, 16, 64));
    tmax = fmaxf(tmax, __shfl_xor(tmax, 32, 64));
    const float mnew = fmaxf(mrow, tmax);
    const float cfac = __expf(mrow - mnew);
    mrow = mnew;
    float tsum = 0.f;
#pragma unroll
    for (int j = 0; j < 4; ++j)
#pragma unroll
      for (int r = 0; r < 4; ++r) {
        const float p = __expf(sc[j][r] - mnew);
        sc[j][r] = p; tsum += p;
      }
    tsum += __shfl_xor(tsum, 16, 64);
    tsum += __shfl_xor(tsum, 32, 64);
    srow = srow * cfac + tsum;
#pragma unroll
    for (int j = 0; j < 4; ++j) {
      const uint lo = (uint)f2bf(sc[j][0]) | ((uint)f2bf(sc[j][1]) << 16);
      const uint hi = (uint)f2bf(sc[j][2]) | ((uint)f2bf(sc[j][3]) << 16);
      *(uint*)&Pl[w][lq * KP + j * 16 + lg * 4]     = lo;
      *(uint*)&Pl[w][lq * KP + j * 16 + lg * 4 + 2] = hi;
    }
    float crow[4];
#pragma unroll
    for (int r = 0; r < 4; ++r) crow[r] = __shfl(cfac, lg * 4 + r, 64);
#pragma unroll
    for (int nt = 0; nt < 2; ++nt)
#pragma unroll
      for (int r = 0; r < 4; ++r) oacc[nt][r] *= crow[r];
#pragma unroll
    for (int ks = 0; ks < 2; ++ks) {
      const bf16x8 pf = *(const bf16x8*)&Pl[w][lq * KP + ks * 32 + lg * 8];
#pragma unroll
      for (int nt = 0; nt < 2; ++nt) {
        const bf16x8 vf = *(const bf16x8*)&Vt[(nt * 16 + lq) * VP + ks * 32 + lg * 8];
        oacc[nt] = __builtin_amdgcn_mfma_f32_16x16x32_bf16(pf, vf, oacc[nt], 0, 0, 0);
      }
    }
  }
  float sinv[4];
#pragma unroll
  for (int r = 0; r < 4; ++r) {
    const float sr = __shfl(srow, lg * 4 + r, 64);
    sinv[r] = 1.f / sr;
  }
#pragma unroll
  for (int r = 0; r < 4; ++r) {
    const int qg = q0 + w * 16 + lg * 4 + r;
    if (qg < LQ_) {
      float* op = O + ((size_t)qg * B_ + b) * 256 + h * DH_;
      op[lq]      = oacc[0][r] * sinv[r];
      op[16 + lq] = oacc[1][r] * sinv[r];
    }
  }
}

// ---------------- residual + LayerNorm: Y = LN(X + R) * g + b ----------------
__global__ __launch_bounds__(256) void ln_kernel(
    const float* __restrict__ X, const float* __restrict__ R,
    const float* __restrict__ g, const float* __restrict__ be,
    float* __restrict__ Y)
{
  const int row = blockIdx.x;
  const int t = threadIdx.x;
  const size_t idx = (size_t)row * D_ + t;
  const float v = X[idx] + R[idx];
  __shared__ float red[4];
  const int wid = t >> 6, lane = t & 63;

  float sum = v;
#pragma unroll
  for (int o = 32; o > 0; o >>= 1) sum += __shfl_xor(sum, o, 64);
  if (lane == 0) red[wid] = sum;
  __syncthreads();
  const float mean = (red[0] + red[1] + red[2] + red[3]) * (1.f / D_);
  const float d = v - mean;
  float sq = d * d;
#pragma unroll
  for (int o = 32; o > 0; o >>= 1) sq += __shfl_xor(sq, o, 64);
  __syncthreads();
  if (lane == 0) red[wid] = sq;
  __syncthreads();
  const float var = (red[0] + red[1] + red[2] + red[3]) * (1.f / D_);
  Y[idx] = d * rsqrtf(var + 1e-5f) * g[t] + be[t];
}

// ---------------- MSDeformAttn sampling (bf16 value; 4 threads per (q,b,h)) ----------------
__global__ __launch_bounds__(256) void msdeform_kernel(
    const float* __restrict__ refp, const float* __restrict__ offb,
    const float* __restrict__ awb, const ushort* __restrict__ value,
    float* __restrict__ out)
{
  const int t  = blockIdx.x * 256 + threadIdx.x;   // < MQ*HEADS_*4
  const int dq = t & 3;            // dh quarter: 8 floats
  const int h  = (t >> 2) & 7;
  const int u  = t >> 5;           // b*LQ_ + q
  const int b  = u / LQ_;
  const int q  = u - b * LQ_;
  const int r  = q * B_ + b;

  float aw[LVLS_ * PTS_];
  const float* ap = awb + (size_t)r * 128 + h * 16;
  float m = -1e30f;
#pragma unroll
  for (int i = 0; i < 16; ++i) { aw[i] = ap[i]; m = fmaxf(m, aw[i]); }
  float s = 0.f;
#pragma unroll
  for (int i = 0; i < 16; ++i) { aw[i] = __expf(aw[i] - m); s += aw[i]; }
  const float inv = 1.f / s;
#pragma unroll
  for (int i = 0; i < 16; ++i) aw[i] *= inv;

  float o[8] = {};
  const int HH[4] = {100, 50, 25, 13};
  const int WW[4] = {100, 50, 25, 13};
  const int ST[4] = {0, 10000, 12500, 13125};
  const float* orow = offb + (size_t)r * 256 + h * (LVLS_ * PTS_ * 2);
  const int dh0 = h * DH_ + dq * 8;

  for (int l = 0; l < LVLS_; ++l) {
    const float4 rf = *(const float4*)(refp + (((size_t)q * B_ + b) * LVLS_ + l) * 4);
    const int W_ = WW[l], H_ = HH[l], s0 = ST[l];
    for (int p = 0; p < PTS_; ++p) {
      const float ox = orow[(l * PTS_ + p) * 2 + 0];
      const float oy = orow[(l * PTS_ + p) * 2 + 1];
      const float lx = rf.x + ox * 0.125f * rf.z;
      const float ly = rf.y + oy * 0.125f * rf.w;
      const float x = lx * W_ - 0.5f;
      const float y = ly * H_ - 0.5f;
      const float x0f = floorf(x), y0f = floorf(y);
      const float wx = x - x0f, wy = y - y0f;
      const int x0 = (int)x0f, y0 = (int)y0f;
      const float a = aw[l * PTS_ + p];
      const float cw[4] = {(1.f - wx) * (1.f - wy) * a, wx * (1.f - wy) * a,
                           (1.f - wx) * wy * a,         wx * wy * a};
      const int cx[4] = {x0, x0 + 1, x0, x0 + 1};
      const int cy[4] = {y0, y0, y0 + 1, y0 + 1};
#pragma unroll
      for (int c = 0; c < 4; ++c) {
        const int xi = cx[c], yi = cy[c];
        if (xi >= 0 && xi < W_ && yi >= 0 && yi < H_) {
          const ushort* vp = value + ((size_t)(s0 + yi * W_ + xi) * B_ + b) * 256 + dh0;
          const float w = cw[c];
          const bf16x8 vv = *(const bf16x8*)vp;   // 16 B
#pragma unroll
          for (int j = 0; j < 8; ++j)
            o[j] = fmaf(w, bf2f(((const ushort*)&vv)[j]), o[j]);
        }
      }
    }
  }
  float* op = out + (size_t)r * 256 + dh0;
  float4 x1; x1.x = o[0]; x1.y = o[1]; x1.z = o[2]; x1.w = o[3];
  float4 x2; x2.x = o[4]; x2.y = o[5]; x2.z = o[6]; x2.w = o[7];
  *(float4*)op = x1;
  *(float4*)(op + 4) = x2;
}

extern "C" void kernel_launch(void* const* d_in, const int* in_sizes, int n_in,
                              void* d_out, int out_size, void* d_ws, size_t ws_size,
                              hipStream_t stream) {
  const float* tgt       = (const float*)d_in[0];
  const float* pos       = (const float*)d_in[1];
  const float* refp      = (const float*)d_in[2];
  const float* memory    = (const float*)d_in[3];
  const float* in_proj_w = (const float*)d_in[6];
  const float* in_proj_b = (const float*)d_in[7];
  const float* sa_out_w  = (const float*)d_in[8];
  const float* sa_out_b  = (const float*)d_in[9];
  const float* off_w     = (const float*)d_in[10];
  const float* off_b     = (const float*)d_in[11];
  const float* aw_w      = (const float*)d_in[12];
  const float* aw_b      = (const float*)d_in[13];
  const float* val_w     = (const float*)d_in[14];
  const float* val_b     = (const float*)d_in[15];
  const float* ca_out_w  = (const float*)d_in[16];
  const float* ca_out_b  = (const float*)d_in[17];
  const float* lin1_w    = (const float*)d_in[18];
  const float* lin1_b    = (const float*)d_in[19];
  const float* lin2_w    = (const float*)d_in[20];
  const float* lin2_b    = (const float*)d_in[21];
  const float* n1g = (const float*)d_in[22];
  const float* n1b = (const float*)d_in[23];
  const float* n2g = (const float*)d_in[24];
  const float* n2b = (const float*)d_in[25];
  const float* n3g = (const float*)d_in[26];
  const float* n3b = (const float*)d_in[27];

  float* ws = (float*)d_ws;
  float* QK    = ws;                               // MQ*512
  float* Vb    = QK   + (size_t)MQ * 512;          // MQ*256
  float* Cb    = Vb   + (size_t)MQ * 256;          // MQ*256
  float* Db    = Cb   + (size_t)MQ * 256;          // MQ*256
  float* tgt1  = Db   + (size_t)MQ * 256;          // MQ*256
  float* tgt2  = tgt1 + (size_t)MQ * 256;          // MQ*256
  float* big   = tgt2 + (size_t)MQ * 256;          // max(MV*128, MQ*1024) floats
  ushort* value = (ushort*)big;                    // MV*256 bf16
  float* mid   = big;   // FFN mid aliases value region (disjoint lifetimes)

  const dim3 blk(256);
  const int gy_q = (MQ + 63) / 64;        // 225
  const int gy_v128 = (MV + 127) / 128;   // 1662
  const int qtiles = (LQ_ + QB - 1) / QB; // 15

  // 1) Q,K projections (input tgt+pos), N=512 — bf16 MFMA 64-tile
  gemm_bf16_64<<<dim3(8, gy_q), blk, 0, stream>>>(tgt, pos, in_proj_w, in_proj_b, QK, MQ, 512, D_, 0);
  // 2) V projection (input tgt), N=256 — bf16 MFMA 64-tile
  gemm_bf16_64<<<dim3(4, gy_q), blk, 0, stream>>>(tgt, nullptr, in_proj_w + 512 * D_, in_proj_b + 512, Vb, MQ, 256, D_, 0);
  // 3) self-attention — bf16 MFMA flash
  attn_mfma_kernel<<<dim3(qtiles, B_ * HEADS_), blk, 0, stream>>>(QK, Vb, Cb);
  // 4) SA out proj — bf16 MFMA 64-tile
  gemm_bf16_64<<<dim3(4, gy_q), blk, 0, stream>>>(Cb, nullptr, sa_out_w, sa_out_b, Db, MQ, 256, D_, 0);
  // 5) tgt1 = LN(tgt + sa; norm2)
  ln_kernel<<<MQ, blk, 0, stream>>>(tgt, Db, n2g, n2b, tgt1);
  // 6) value projection over memory — bf16 MFMA 128-tile (R5 variant), bf16 out
  gemm_bf16_kernel<<<dim3(2, gy_v128), blk, 0, stream>>>(memory, nullptr, val_w, val_b, (float*)value, MV, 256, D_, 0, 1);
  // 7) sampling offsets (input tgt1+pos) — f32 for position precision
  gemm_bias_kernel<<<dim3(4, gy_q), blk, 0, stream>>>(tgt1, pos, off_w, off_b, QK, MQ, 256, D_, 0);
  // 8) attention-weight logits — bf16 64-tile (softmax-tolerant)
  gemm_bf16_64<<<dim3(2, gy_q), blk, 0, stream>>>(tgt1, pos, aw_w, aw_b, Vb, MQ, 128, D_, 0);
  // 9) deformable sampling -> Cb  (bf16 value gather)
  msdeform_kernel<<<(MQ * HEADS_ * 4 + 255) / 256, blk, 0, stream>>>(refp, QK, Vb, value, Cb);
  // 10) CA out proj — bf16 MFMA 64-tile
  gemm_bf16_64<<<dim3(4, gy_q), blk, 0, stream>>>(Cb, nullptr, ca_out_w, ca_out_b, Db, MQ, 256, D_, 0);
  // 11) tgt2 = LN(tgt1 + ca; norm1)
  ln_kernel<<<MQ, blk, 0, stream>>>(tgt1, Db, n1g, n1b, tgt2);
  // 12) FFN lin1 + relu -> mid — bf16 MFMA 64-tile
  gemm_bf16_64<<<dim3(16, gy_q), blk, 0, stream>>>(tgt2, nullptr, lin1_w, lin1_b, mid, MQ, DFF_, D_, 1);
  // 13) FFN lin2 -> Db — bf16 MFMA 64-tile (K=1024)
  gemm_bf16_64<<<dim3(4, gy_q), blk, 0, stream>>>(mid, nullptr, lin2_w, lin2_b, Db, MQ, 256, DFF_, 0);
  // 14) out = LN(tgt2 + ffn; norm3)
  ln_kernel<<<MQ, blk, 0, stream>>>(tgt2, Db, n3g, n3b, (float*)d_out);
}